// Round 9
// baseline (4995.115 us; speedup 1.0000x reference)
//
#include <hip/hip_runtime.h>
#include <hip/hip_fp16.h>
#include <math.h>

#define B_ 64
#define T_ 512
#define F_ 128
#define H_ 512
#define NBLK 96
#define SPIN_MAX (1 << 20)
#define GUARD_RETRY 4096

typedef _Float16 f16x8 __attribute__((ext_vector_type(8)));
typedef float f32x4 __attribute__((ext_vector_type(4)));
typedef int   i32x4 __attribute__((ext_vector_type(4)));

__device__ __forceinline__ unsigned short f2h(float f) {
    return __half_as_ushort(__float2half(f));   // RN
}
__device__ __forceinline__ float h2f(unsigned short u) {
    return __half2float(__ushort_as_half(u));
}

// ---------------------------------------------------------------------------
// One-time input transform: input[b][t][f] -> fp16 kquad stream
// xs[t][kp2=f>>2][b][{dw0,dw1}]; dw_p = fp16(4kp2+2p) | fp16(4kp2+2p+1)<<16.
// (xs is UNTAGGED: static data, written before the scan kernel.)
// ---------------------------------------------------------------------------
__global__ void transpose_x(const float* __restrict__ in, unsigned* __restrict__ xs) {
    const int t = blockIdx.x;
    for (int idx = threadIdx.x; idx < B_ * F_ / 4; idx += blockDim.x) {
        const int kp2 = idx >> 6;       // 0..31
        const int bb = idx & 63;
        const float* src = in + (size_t)bb * T_ * F_ + (size_t)t * F_ + 4 * kp2;
        const unsigned h0 = f2h(src[0]), h1 = f2h(src[1]);
        const unsigned h2 = f2h(src[2]), h3 = f2h(src[3]);
        const unsigned dw0 = h0 | (h1 << 16);
        const unsigned dw1 = h2 | (h3 << 16);
        *(unsigned long long*)(xs + (size_t)t * 4096 + (size_t)kp2 * 128 + bb * 2) =
            ((unsigned long long)dw1 << 32) | dw0;
    }
}

// Fast device transcendentals (proven R4).
__device__ __forceinline__ float sigmoid_(float x) {
    return __builtin_amdgcn_rcpf(1.0f + __expf(-x));
}
__device__ __forceinline__ float tanh_(float x) {
    return 1.0f - 2.0f * __builtin_amdgcn_rcpf(1.0f + __expf(2.0f * x));
}

// Device-coherent ops (relaxed agent-scope atomics -> sc1). Proven R0-R7.
__device__ __forceinline__ unsigned long long loadc_u64(const unsigned* p) {
    return __hip_atomic_load((const unsigned long long*)p, __ATOMIC_RELAXED,
                             __HIP_MEMORY_SCOPE_AGENT);
}
__device__ __forceinline__ void storec_u64(unsigned* p, unsigned long long v) {
    __hip_atomic_store((unsigned long long*)p, v, __ATOMIC_RELAXED,
                       __HIP_MEMORY_SCOPE_AGENT);
}
__device__ __forceinline__ void storec_f(float* p, float v) {
    __hip_atomic_store(p, v, __ATOMIC_RELAXED, __HIP_MEMORY_SCOPE_AGENT);
}
__device__ __forceinline__ float loadc_f(const float* p) {
    return __hip_atomic_load(p, __ATOMIC_RELAXED, __HIP_MEMORY_SCOPE_AGENT);
}
__device__ __forceinline__ int loadc_i(const int* p) {
    return __hip_atomic_load(p, __ATOMIC_RELAXED, __HIP_MEMORY_SCOPE_AGENT);
}
__device__ __forceinline__ void storec_i(int* p, int v) {
    __hip_atomic_store(p, v, __ATOMIC_RELAXED, __HIP_MEMORY_SCOPE_AGENT);
}

// ---------------------------------------------------------------------------
// Flat 96-slot barrier, two flavors.
// gbar_nd: NO vmcnt drain before arrival — data freshness is certified by
// in-band tags instead, so the ~0.9us store-ack leaves the critical path.
// (Stores are ISSUED before __syncthreads; the flag follows in issue order;
// a flag that outruns data in the fabric is absorbed by consumer tag-retry.)
// gbar_drain: classic R4 barrier (ack included) for the rare final syncs.
// ---------------------------------------------------------------------------
__device__ __forceinline__ void gbar_nd(int* __restrict__ slots, int bid,
                                        int tid, int e) {
    __syncthreads();
    if (tid == 0) storec_i(&slots[bid * 16], e);
    if (tid < NBLK) {
        int g = 0;
        while (loadc_i(&slots[tid * 16]) < e && ++g < SPIN_MAX)
            __builtin_amdgcn_s_sleep(1);
    }
    __syncthreads();
}
__device__ __forceinline__ void gbar_drain(int* __restrict__ slots, int bid,
                                           int tid, int e) {
    asm volatile("s_waitcnt vmcnt(0) lgkmcnt(0)" ::: "memory");
    __syncthreads();
    if (tid == 0) storec_i(&slots[bid * 16], e);
    if (tid < NBLK) {
        int g = 0;
        while (loadc_i(&slots[tid * 16]) < e && ++g < SPIN_MAX)
            __builtin_amdgcn_s_sleep(1);
    }
    __syncthreads();
}

// ---------------------------------------------------------------------------
// Tagged h format: [3 layers][4 slots][128 kp2][64 b][4 dw], where the 4 dw
// are two u64: {D(2 fp16) | tag<<32}, {D2(2 fp16) | tag<<32}. tag = t+1 for
// h(t). Single-u64 atomic stores cannot tear; per-u64 tags self-certify.
//
// Per-layer scan (lag-1: layer l runs step t at epoch s = t + l):
//   [epoch body] issue x loads -> issue h loads (slot (t+3)&3) ->
//   verify tags (x: t+1 if tagged; h: t), bounded retry ->
//   x-MFMAs -> h-MFMAs -> finalize -> tagged h stores slot t&3 ->
//   gbar_nd (no drain).
// WAR: 4 slots + <1 epoch barrier drift => overwrite is 4 epochs after last
// read; late-landing stores (~1us past release) are far inside that window.
// ---------------------------------------------------------------------------
template <int NKX, bool XTAG>
__device__ void scan_layer(const unsigned* __restrict__ xb,
                           unsigned* __restrict__ hbuf,   // [4][32768] dw
                           int* __restrict__ slots, int bid, int tid,
                           const unsigned short* __restrict__ wfrag,
                           const float (&bias)[4][4], int lane, int q, int fb,
                           int cb, int layer) {
    union Frag { i32x4 i4; f16x8 s; };
    float c_reg[4] = {0.f, 0.f, 0.f, 0.f};
    const int ho = fb * 4;                 // tagged-entry lane base (dwords)
    const int xo_plain = q * 256 + fb * 2; // layer0 xs layout (dwords)
    int hstE[4];
#pragma unroll
    for (int rg = 0; rg < 4; ++rg) hstE[rg] = (cb * 4 + rg) * 256 + fb * 4;

    for (int s = 0; s < T_ + 2; ++s) {
        const int t = s - layer;
        if (t >= 0 && t < T_) {
            unsigned long long vh[32][2];             // [entry][lo,hi]
            unsigned long long vx[XTAG ? 32 : NKX][2];

            const unsigned* hsl = hbuf + (size_t)((t + 3) & 3) * 32768 + ho;
            const unsigned* xsl = XTAG ? (xb + (size_t)(t & 3) * 32768 + ho)
                                       : (xb + (size_t)t * 4096 + xo_plain);

            auto issue_x = [&]() {
                if constexpr (XTAG) {
#pragma unroll
                    for (int i = 0; i < 16; ++i) {
                        const unsigned* e0 = xsl + (8 * i + 2 * q) * 256;
                        vx[2 * i][0]     = loadc_u64(e0);
                        vx[2 * i][1]     = loadc_u64(e0 + 2);
                        vx[2 * i + 1][0] = loadc_u64(e0 + 256);
                        vx[2 * i + 1][1] = loadc_u64(e0 + 258);
                    }
                } else {
#pragma unroll
                    for (int i = 0; i < NKX; ++i) {
                        vx[i][0] = *(const unsigned long long*)(xsl + i * 1024);
                        vx[i][1] = *(const unsigned long long*)(xsl + i * 1024 + 128);
                    }
                }
            };
            auto issue_h = [&]() {
#pragma unroll
                for (int j = 0; j < 16; ++j) {
                    const unsigned* e0 = hsl + (8 * j + 2 * q) * 256;
                    vh[2 * j][0]     = loadc_u64(e0);
                    vh[2 * j][1]     = loadc_u64(e0 + 2);
                    vh[2 * j + 1][0] = loadc_u64(e0 + 256);
                    vh[2 * j + 1][1] = loadc_u64(e0 + 258);
                }
            };

            issue_x();
            issue_h();

            // ---- verify tags; bounded retry (stale reads are rare: stores
            // were issued >= one barrier round trip ago).
            const unsigned htag = (unsigned)t;
            const unsigned xtag = (unsigned)(t + 1);
            int guard = 0;
            for (;;) {
                int ok = 1;
#pragma unroll
                for (int e = 0; e < 32; ++e)
                    ok &= ((unsigned)(vh[e][0] >> 32) == htag) &
                          ((unsigned)(vh[e][1] >> 32) == htag);
                if constexpr (XTAG) {
#pragma unroll
                    for (int e = 0; e < 32; ++e)
                        ok &= ((unsigned)(vx[e][0] >> 32) == xtag) &
                              ((unsigned)(vx[e][1] >> 32) == xtag);
                }
                if (__all(ok)) break;
                if (++guard > GUARD_RETRY) break;   // fail-fast, never hang
                issue_x();
                issue_h();
            }

            f32x4 acc[4] = {{0.f,0.f,0.f,0.f},{0.f,0.f,0.f,0.f},
                            {0.f,0.f,0.f,0.f},{0.f,0.f,0.f,0.f}};
            // ---- x MFMAs (ksteps 0..NKX-1)
#pragma unroll
            for (int i = 0; i < NKX; ++i) {
                Frag Bf, A0, A1, A2, A3;
                if constexpr (XTAG) {
                    Bf.i4[0] = (int)(unsigned)vx[2 * i][0];
                    Bf.i4[1] = (int)(unsigned)vx[2 * i][1];
                    Bf.i4[2] = (int)(unsigned)vx[2 * i + 1][0];
                    Bf.i4[3] = (int)(unsigned)vx[2 * i + 1][1];
                } else {
                    Bf.i4[0] = (int)(unsigned)vx[i][0];
                    Bf.i4[1] = (int)(unsigned)(vx[i][0] >> 32);
                    Bf.i4[2] = (int)(unsigned)vx[i][1];
                    Bf.i4[3] = (int)(unsigned)(vx[i][1] >> 32);
                }
                A0.i4 = *(const i32x4*)&wfrag[i * 2048 + lane * 8];
                A1.i4 = *(const i32x4*)&wfrag[i * 2048 + 512 + lane * 8];
                A2.i4 = *(const i32x4*)&wfrag[i * 2048 + 1024 + lane * 8];
                A3.i4 = *(const i32x4*)&wfrag[i * 2048 + 1536 + lane * 8];
                acc[0] = __builtin_amdgcn_mfma_f32_16x16x32_f16(A0.s, Bf.s, acc[0], 0, 0, 0);
                acc[1] = __builtin_amdgcn_mfma_f32_16x16x32_f16(A1.s, Bf.s, acc[1], 0, 0, 0);
                acc[2] = __builtin_amdgcn_mfma_f32_16x16x32_f16(A2.s, Bf.s, acc[2], 0, 0, 0);
                acc[3] = __builtin_amdgcn_mfma_f32_16x16x32_f16(A3.s, Bf.s, acc[3], 0, 0, 0);
            }
            // ---- h MFMAs (ksteps NKX..NKX+15)
#pragma unroll
            for (int j = 0; j < 16; ++j) {
                Frag Bf, A0, A1, A2, A3;
                Bf.i4[0] = (int)(unsigned)vh[2 * j][0];
                Bf.i4[1] = (int)(unsigned)vh[2 * j][1];
                Bf.i4[2] = (int)(unsigned)vh[2 * j + 1][0];
                Bf.i4[3] = (int)(unsigned)vh[2 * j + 1][1];
                const int i = NKX + j;
                A0.i4 = *(const i32x4*)&wfrag[i * 2048 + lane * 8];
                A1.i4 = *(const i32x4*)&wfrag[i * 2048 + 512 + lane * 8];
                A2.i4 = *(const i32x4*)&wfrag[i * 2048 + 1024 + lane * 8];
                A3.i4 = *(const i32x4*)&wfrag[i * 2048 + 1536 + lane * 8];
                acc[0] = __builtin_amdgcn_mfma_f32_16x16x32_f16(A0.s, Bf.s, acc[0], 0, 0, 0);
                acc[1] = __builtin_amdgcn_mfma_f32_16x16x32_f16(A1.s, Bf.s, acc[1], 0, 0, 0);
                acc[2] = __builtin_amdgcn_mfma_f32_16x16x32_f16(A2.s, Bf.s, acc[2], 0, 0, 0);
                acc[3] = __builtin_amdgcn_mfma_f32_16x16x32_f16(A3.s, Bf.s, acc[3], 0, 0, 0);
            }

            // ---- finalize; tagged h stores into slot t&3 (no fence after:
            // the barrier flag may outrun them; consumer tags absorb it).
#pragma unroll
            for (int rg = 0; rg < 4; ++rg) {
                float a[4];
#pragma unroll
                for (int g = 0; g < 4; ++g) a[g] = bias[rg][g] + acc[rg][g];
                const float ig = sigmoid_(a[0]);
                const float fg = sigmoid_(a[1]);
                const float gg = tanh_(a[2]);
                const float og = sigmoid_(a[3]);
                c_reg[rg] = fg * c_reg[rg] + ig * gg;
                const float hv = og * tanh_(c_reg[rg]);
                const unsigned P0 = (unsigned)f2h(hv);
                const unsigned P1 = (unsigned)__shfl_xor((int)P0, 16, 64) & 0xFFFFu;
                const unsigned D  = P0 | (P1 << 16);
                const unsigned D2 = (unsigned)__shfl_xor((int)D, 32, 64);
                if (q == 0) {
                    unsigned* eb = hbuf + (size_t)(t & 3) * 32768 + hstE[rg];
                    const unsigned long long tg = (unsigned long long)(t + 1) << 32;
                    storec_u64(eb, tg | D);
                    storec_u64(eb + 2, tg | D2);
                }
            }
        }
        gbar_nd(slots, bid, tid, s + 1);
    }
}

// ---------------------------------------------------------------------------
// Persistent layer-pipelined LSTM. Block (layer=bid>>5, cb=bid&31) owns 64
// gate-rows (cols cb*16..+15 x gates i,f,g,o); wave w owns b-tile
// [16w,16w+16). R4 skeleton; in-band tags replace the barrier's store-ack.
// ---------------------------------------------------------------------------
__global__ void __launch_bounds__(256, 1) lstm_scan(
    const unsigned* __restrict__ xs, unsigned* __restrict__ hbf,
    float* __restrict__ h1s, float* __restrict__ out,
    int* __restrict__ bar_slots,
    const float* __restrict__ Wih0, const float* __restrict__ Whh0,
    const float* __restrict__ bih0, const float* __restrict__ bhh0,
    const float* __restrict__ Wih1, const float* __restrict__ Whh1,
    const float* __restrict__ bih1, const float* __restrict__ bhh1,
    const float* __restrict__ Wih2, const float* __restrict__ Whh2,
    const float* __restrict__ bih2, const float* __restrict__ bhh2,
    const float* __restrict__ fcW1, const float* __restrict__ fcb1,
    const float* __restrict__ fcW2, const float* __restrict__ fcb2) {
    __shared__ unsigned short wfrag[32 * 2048];   // [kstep][rg 4][512], 128 KB
    __shared__ float redsc[4 * 64];               // FC-head reduction only

    const float* WihA[3] = {Wih0, Wih1, Wih2};
    const float* WhhA[3] = {Whh0, Whh1, Whh2};
    const float* bihA[3] = {bih0, bih1, bih2};
    const float* bhhA[3] = {bhh0, bhh1, bhh2};

    const int tid   = threadIdx.x;
    const int bid   = blockIdx.x;
    const int layer = bid >> 5;
    const int cb    = bid & 31;
    const int c0    = cb * 16;
    const int lane  = tid & 63;
    const int w     = __builtin_amdgcn_readfirstlane(tid >> 6);
    const int KX    = (layer == 0) ? F_ : H_;
    const int NK    = KX / 32 + 16;

    const float* wih = WihA[layer];
    const float* whh = WhhA[layer];

    // ---- Stage weights once: fp16 RN, A-frag order, 4 row-groups per kstep.
    for (int idx = tid; idx < NK * 2048; idx += 256) {
        const int i = idx >> 11, rem = idx & 2047;
        const int rg = rem >> 9, r2 = rem & 511;
        const int l = r2 >> 3, j = r2 & 7;
        const int m = l & 15;
        const int grow = (m & 3) * 512 + c0 + rg * 4 + (m >> 2);
        const int k = i * 32 + (l >> 4) * 8 + j;
        const float f = (k < KX) ? wih[(size_t)grow * KX + k]
                                 : whh[(size_t)grow * 512 + (k - KX)];
        wfrag[i * 2048 + rg * 512 + l * 8 + j] = f2h(f);
    }
    __syncthreads();

    // Finalize-role constants: lane owns (b = 16w + n, cols c0+rg*4+q).
    const int fb = w * 16 + (lane & 15);
    const int q  = lane >> 4;
    float bias[4][4];
#pragma unroll
    for (int rg = 0; rg < 4; ++rg)
#pragma unroll
        for (int g = 0; g < 4; ++g)
            bias[rg][g] = bihA[layer][g * 512 + c0 + rg * 4 + q] +
                          bhhA[layer][g * 512 + c0 + rg * 4 + q];

    // Buffers. hbf: [3 layers][4 slots][32768 dw] tagged entries.
    unsigned* hbuf = hbf + (size_t)layer * 4 * 32768;
    const unsigned* xb =
        (layer == 0) ? xs : (hbf + (size_t)(layer - 1) * 4 * 32768);

    if (layer == 0)
        scan_layer<4, false>(xb, hbuf, bar_slots, bid, tid, wfrag, bias, lane,
                             q, fb, cb, 0);
    else if (layer == 1)
        scan_layer<16, true>(xb, hbuf, bar_slots, bid, tid, wfrag, bias, lane,
                             q, fb, cb, 1);
    else
        scan_layer<16, true>(xb, hbuf, bar_slots, bid, tid, wfrag, bias, lane,
                             q, fb, cb, 2);

    // ---- FC head. h2 = layer-2 h(511) = slot 3, tagged entries, tag 512.
    const int fcb = tid & 63;
    if (bid < 64) {
        const unsigned* h2b = hbf + (size_t)2 * 4 * 32768 + (size_t)3 * 32768;
        unsigned long long ef[32][2];
        int guard = 0;
        for (;;) {
#pragma unroll
            for (int j = 0; j < 32; ++j) {
                const unsigned* e0 = h2b + (size_t)(w * 32 + j) * 256 + fcb * 4;
                ef[j][0] = loadc_u64(e0);
                ef[j][1] = loadc_u64(e0 + 2);
            }
            int ok = 1;
#pragma unroll
            for (int j = 0; j < 32; ++j)
                ok &= ((unsigned)(ef[j][0] >> 32) == (unsigned)T_) &
                      ((unsigned)(ef[j][1] >> 32) == (unsigned)T_);
            if (__all(ok)) break;
            if (++guard > GUARD_RETRY) break;
        }
        float part = 0.0f;
        const float* wrow = fcW1 + (size_t)bid * H_ + w * 128;
#pragma unroll
        for (int j = 0; j < 32; ++j) {
            const unsigned d1 = (unsigned)ef[j][0], d2 = (unsigned)ef[j][1];
            part = fmaf(wrow[4 * j],     h2f((unsigned short)(d1 & 0xFFFFu)), part);
            part = fmaf(wrow[4 * j + 1], h2f((unsigned short)(d1 >> 16)), part);
            part = fmaf(wrow[4 * j + 2], h2f((unsigned short)(d2 & 0xFFFFu)), part);
            part = fmaf(wrow[4 * j + 3], h2f((unsigned short)(d2 >> 16)), part);
        }
        redsc[w * 64 + fcb] = part;
        __syncthreads();
        if (tid < 64) {
            float acc2 = fcb1[bid] + redsc[tid] + redsc[64 + tid] +
                         redsc[128 + tid] + redsc[192 + tid];
            storec_f(&h1s[bid * B_ + tid], fmaxf(acc2, 0.0f));
        }
    }
    gbar_drain(bar_slots, bid, tid, T_ + 3);   // h1s visible after this
    if (bid == 0 && tid < 64) {
        float acc2 = fcb2[0];
#pragma unroll
        for (int c = 0; c < 64; ++c)
            acc2 = fmaf(fcW2[c], loadc_f(&h1s[c * B_ + tid]), acc2);
        out[tid] = fmaxf(acc2, 0.0f);
    }
}

// ---------------------------------------------------------------------------
extern "C" void kernel_launch(void* const* d_in, const int* in_sizes, int n_in,
                              void* d_out, int out_size, void* d_ws, size_t ws_size,
                              hipStream_t stream) {
    const float* in    = (const float*)d_in[0];
    const float* Wih0  = (const float*)d_in[1];
    const float* Whh0  = (const float*)d_in[2];
    const float* bih0  = (const float*)d_in[3];
    const float* bhh0  = (const float*)d_in[4];
    const float* Wih1  = (const float*)d_in[5];
    const float* Whh1  = (const float*)d_in[6];
    const float* bih1  = (const float*)d_in[7];
    const float* bhh1  = (const float*)d_in[8];
    const float* Wih2  = (const float*)d_in[9];
    const float* Whh2  = (const float*)d_in[10];
    const float* bih2  = (const float*)d_in[11];
    const float* bhh2  = (const float*)d_in[12];
    const float* fcW1  = (const float*)d_in[13];
    const float* fcb1  = (const float*)d_in[14];
    const float* fcW2  = (const float*)d_in[15];
    const float* fcb2  = (const float*)d_in[16];
    float* outp = (float*)d_out;

    unsigned* xs  = (unsigned*)d_ws;                   // [T][4096] dw     8 MB
    unsigned* hbf = xs + (size_t)T_ * 4096;            // [3][4][32768] 1.5 MB
    float* h1s = (float*)(hbf + (size_t)3 * 4 * 32768);// [64][64]       16 KB
    int* bar_slots = (int*)(h1s + 64 * 64);            // NBLK*16 ints

    // zero tags + flags + h1s each replay (graph-capture safe re-arm)
    hipMemsetAsync(hbf, 0,
                   ((size_t)3 * 4 * 32768 + 64 * 64 + NBLK * 16 + 16) *
                       sizeof(int),
                   stream);

    transpose_x<<<dim3(T_), dim3(256), 0, stream>>>(in, xs);

    void* args[] = {
        (void*)&xs, (void*)&hbf, (void*)&h1s, (void*)&outp, (void*)&bar_slots,
        (void*)&Wih0, (void*)&Whh0, (void*)&bih0, (void*)&bhh0,
        (void*)&Wih1, (void*)&Whh1, (void*)&bih1, (void*)&bhh1,
        (void*)&Wih2, (void*)&Whh2, (void*)&bih2, (void*)&bhh2,
        (void*)&fcW1, (void*)&fcb1, (void*)&fcW2, (void*)&fcb2};
    hipLaunchCooperativeKernel((void*)lstm_scan, dim3(NBLK), dim3(256), args, 0, stream);
}

// Round 10
// 2658.333 us; speedup vs baseline: 1.8790x; 1.8790x over previous
//
#include <hip/hip_runtime.h>
#include <hip/hip_fp16.h>
#include <math.h>

#define B_ 64
#define T_ 512
#define F_ 128
#define H_ 512
#define NBLK 96
#define SPIN_MAX (1 << 20)

typedef _Float16 f16x8 __attribute__((ext_vector_type(8)));
typedef float f32x4 __attribute__((ext_vector_type(4)));
typedef int   i32x4 __attribute__((ext_vector_type(4)));

__device__ __forceinline__ unsigned short f2h(float f) {
    return __half_as_ushort(__float2half(f));   // RN
}
__device__ __forceinline__ float h2f(unsigned short u) {
    return __half2float(__ushort_as_half(u));
}

// ---------------------------------------------------------------------------
// One-time input transform: input[b][t][f] -> fp16 kquad stream
// xs[t][kp2=f>>2][b][{dw0,dw1}]; dw_p = fp16(4kp2+2p) | fp16(4kp2+2p+1)<<16.
// ---------------------------------------------------------------------------
__global__ void transpose_x(const float* __restrict__ in, unsigned* __restrict__ xs) {
    const int t = blockIdx.x;
    for (int idx = threadIdx.x; idx < B_ * F_ / 4; idx += blockDim.x) {
        const int kp2 = idx >> 6;       // 0..31
        const int bb = idx & 63;
        const float* src = in + (size_t)bb * T_ * F_ + (size_t)t * F_ + 4 * kp2;
        const unsigned h0 = f2h(src[0]), h1 = f2h(src[1]);
        const unsigned h2 = f2h(src[2]), h3 = f2h(src[3]);
        const unsigned dw0 = h0 | (h1 << 16);
        const unsigned dw1 = h2 | (h3 << 16);
        *(unsigned long long*)(xs + (size_t)t * 4096 + (size_t)kp2 * 128 + bb * 2) =
            ((unsigned long long)dw1 << 32) | dw0;
    }
}

// Fast device transcendentals (v_exp_f32 + v_rcp_f32, ~1e-7 rel err; fp16
// datapath quantization dominates). Proven R4.
__device__ __forceinline__ float sigmoid_(float x) {
    return __builtin_amdgcn_rcpf(1.0f + __expf(-x));
}
__device__ __forceinline__ float tanh_(float x) {
    return 1.0f - 2.0f * __builtin_amdgcn_rcpf(1.0f + __expf(2.0f * x));
}

// Device-coherent ops (relaxed agent-scope atomics -> sc1). Proven R0-R9.
__device__ __forceinline__ unsigned long long loadc_u64(const unsigned* p) {
    return __hip_atomic_load((const unsigned long long*)p, __ATOMIC_RELAXED,
                             __HIP_MEMORY_SCOPE_AGENT);
}
__device__ __forceinline__ unsigned loadc_u32(const unsigned* p) {
    return __hip_atomic_load(p, __ATOMIC_RELAXED, __HIP_MEMORY_SCOPE_AGENT);
}
__device__ __forceinline__ void storec_u64(unsigned* p, unsigned long long v) {
    __hip_atomic_store((unsigned long long*)p, v, __ATOMIC_RELAXED,
                       __HIP_MEMORY_SCOPE_AGENT);
}
__device__ __forceinline__ void storec_f(float* p, float v) {
    __hip_atomic_store(p, v, __ATOMIC_RELAXED, __HIP_MEMORY_SCOPE_AGENT);
}
__device__ __forceinline__ float loadc_f(const float* p) {
    return __hip_atomic_load(p, __ATOMIC_RELAXED, __HIP_MEMORY_SCOPE_AGENT);
}
__device__ __forceinline__ int loadc_i(const int* p) {
    return __hip_atomic_load(p, __ATOMIC_RELAXED, __HIP_MEMORY_SCOPE_AGENT);
}
__device__ __forceinline__ void storec_i(int* p, int v) {
    __hip_atomic_store(p, v, __ATOMIC_RELAXED, __HIP_MEMORY_SCOPE_AGENT);
}

// ---------------------------------------------------------------------------
// Flat all-to-all grid barrier: each block publishes its slot after a full
// vmcnt drain (R9 proved the drain is REQUIRED: it is the data-visibility
// wait, detection merely overlaps it), then 96 threads poll one slot each.
// ---------------------------------------------------------------------------
__device__ __forceinline__ void gbar(int* __restrict__ slots, int bid, int tid, int e) {
    asm volatile("s_waitcnt vmcnt(0) lgkmcnt(0)" ::: "memory");
    __syncthreads();
    if (tid == 0) storec_i(&slots[bid * 16], e);
    if (tid < NBLK) {
        int g = 0;
        while (loadc_i(&slots[tid * 16]) < e && ++g < SPIN_MAX)
            __builtin_amdgcn_s_sleep(1);
    }
    __syncthreads();
}

// ---------------------------------------------------------------------------
// One step's GEMM: D[4 x 16 gate-rows][16 b] over K = [x-seg|h-seg].
// Single fp16, 64 gate-rows/block, 32 blocks/layer.
// B = fp16 kquad stream; lane (b=16w+n, oct=lane>>4) loads 2 u64 per kstep.
// PD=16 pipeline: 32 loads (256 B/lane) in flight covering sc1 latency.
// ---------------------------------------------------------------------------
template <int NKX, bool XCOH>
__device__ __forceinline__ void step_mfma(const unsigned* __restrict__ xs_l,
                                          const unsigned* __restrict__ hs_l,
                                          const unsigned short* wfrag,
                                          const int lane, f32x4 (&acc)[4]) {
    constexpr int NK = NKX + 16;      // total ksteps (K/32)
    constexpr int PD = 16;            // pipeline depth
    unsigned long long v[PD][2];      // [pipe][pp]

    auto load2 = [&](unsigned long long* d, int i) {
        const unsigned* p = (i < NKX) ? (xs_l + (size_t)i * 1024)
                                      : (hs_l + (size_t)(i - NKX) * 1024);
        if ((i < NKX) ? XCOH : true) {
            d[0] = loadc_u64(p);
            d[1] = loadc_u64(p + 128);
        } else {
            d[0] = *(const unsigned long long*)p;
            d[1] = *(const unsigned long long*)(p + 128);
        }
    };

#pragma unroll
    for (int p = 0; p < PD; ++p) load2(v[p], p);

#pragma unroll
    for (int i = 0; i < NK; ++i) {
        union Frag { i32x4 i4; f16x8 s; } Bf, A0, A1, A2, A3;
        const unsigned long long* d = v[i % PD];
        Bf.i4[0] = (int)(unsigned)d[0];
        Bf.i4[1] = (int)(unsigned)(d[0] >> 32);
        Bf.i4[2] = (int)(unsigned)d[1];
        Bf.i4[3] = (int)(unsigned)(d[1] >> 32);
        if (i + PD < NK) load2(v[i % PD], i + PD);
        A0.i4 = *(const i32x4*)&wfrag[i * 2048 + lane * 8];
        A1.i4 = *(const i32x4*)&wfrag[i * 2048 + 512 + lane * 8];
        A2.i4 = *(const i32x4*)&wfrag[i * 2048 + 1024 + lane * 8];
        A3.i4 = *(const i32x4*)&wfrag[i * 2048 + 1536 + lane * 8];
        acc[0] = __builtin_amdgcn_mfma_f32_16x16x32_f16(A0.s, Bf.s, acc[0], 0, 0, 0);
        acc[1] = __builtin_amdgcn_mfma_f32_16x16x32_f16(A1.s, Bf.s, acc[1], 0, 0, 0);
        acc[2] = __builtin_amdgcn_mfma_f32_16x16x32_f16(A2.s, Bf.s, acc[2], 0, 0, 0);
        acc[3] = __builtin_amdgcn_mfma_f32_16x16x32_f16(A3.s, Bf.s, acc[3], 0, 0, 0);
    }
}

// ---------------------------------------------------------------------------
// Persistent layer-pipelined LSTM scan. Block (layer=bid>>5, cb=bid&31) owns
// 64 gate-rows (cols cb*16..+15 x gates i,f,g,o); wave w owns b-tile
// [16w,16w+16). Lane (n,q) finalizes (b=16w+n, cols c0+rg*4+q, rg=0..3)
// in-register; h written as fp16 kquad stream (next step's B layout).
//
// Session floor note (R4-R9): epoch = data-visibility (~1.8us, physical per
// R9) || detect (~1.4us) + h-load (~0.9us) + compute (~0.8us) ~= 5us. All
// restructurings of this chain (per-wave flags R6, split barrier R7, L2
// placement R5, in-band tags R8/R9) measured neutral, worse, or faulted.
// ---------------------------------------------------------------------------
__global__ void __launch_bounds__(256, 1) lstm_scan(
    const unsigned* __restrict__ xs, unsigned* __restrict__ hbf,
    float* __restrict__ h1s, float* __restrict__ out,
    int* __restrict__ bar_slots,
    const float* __restrict__ Wih0, const float* __restrict__ Whh0,
    const float* __restrict__ bih0, const float* __restrict__ bhh0,
    const float* __restrict__ Wih1, const float* __restrict__ Whh1,
    const float* __restrict__ bih1, const float* __restrict__ bhh1,
    const float* __restrict__ Wih2, const float* __restrict__ Whh2,
    const float* __restrict__ bih2, const float* __restrict__ bhh2,
    const float* __restrict__ fcW1, const float* __restrict__ fcb1,
    const float* __restrict__ fcW2, const float* __restrict__ fcb2) {
    __shared__ unsigned short wfrag[32 * 2048];   // [kstep][rg 4][512], 128 KB
    __shared__ float redsc[4 * 64];               // FC-head reduction only

    const float* WihA[3] = {Wih0, Wih1, Wih2};
    const float* WhhA[3] = {Whh0, Whh1, Whh2};
    const float* bihA[3] = {bih0, bih1, bih2};
    const float* bhhA[3] = {bhh0, bhh1, bhh2};

    const int tid   = threadIdx.x;
    const int bid   = blockIdx.x;
    const int layer = bid >> 5;
    const int cb    = bid & 31;
    const int c0    = cb * 16;
    const int lane  = tid & 63;
    const int w     = __builtin_amdgcn_readfirstlane(tid >> 6);
    const int KX    = (layer == 0) ? F_ : H_;
    const int NK    = KX / 32 + 16;

    const float* wih = WihA[layer];
    const float* whh = WhhA[layer];

    // ---- Stage weights once: fp16 RN, A-frag order, 4 row-groups per kstep.
    for (int idx = tid; idx < NK * 2048; idx += 256) {
        const int i = idx >> 11, rem = idx & 2047;
        const int rg = rem >> 9, r2 = rem & 511;
        const int l = r2 >> 3, j = r2 & 7;
        const int m = l & 15;
        const int grow = (m & 3) * 512 + c0 + rg * 4 + (m >> 2);
        const int k = i * 32 + (l >> 4) * 8 + j;
        const float f = (k < KX) ? wih[(size_t)grow * KX + k]
                                 : whh[(size_t)grow * 512 + (k - KX)];
        wfrag[i * 2048 + rg * 512 + l * 8 + j] = f2h(f);
    }
    __syncthreads();

    // Finalize-role constants: lane owns (b = 16w + n, cols c0+rg*4+q).
    const int fb = w * 16 + (lane & 15);
    const int q  = lane >> 4;
    float bias[4][4];
#pragma unroll
    for (int rg = 0; rg < 4; ++rg)
#pragma unroll
        for (int g = 0; g < 4; ++g)
            bias[rg][g] = bihA[layer][g * 512 + c0 + rg * 4 + q] +
                          bhhA[layer][g * 512 + c0 + rg * 4 + q];

    // h buffers: [layer][parity][kp2 128][b 64][2 dw] dwords (fp16 stream).
    unsigned* hb_l = hbf + (size_t)layer * 32768;
    const unsigned* hb_in = hbf + (size_t)(layer - 1) * 32768;
    int hstore[4];
#pragma unroll
    for (int rg = 0; rg < 4; ++rg) hstore[rg] = (cb * 4 + rg) * 128 + fb * 2;

    float c_reg[4] = {0.0f, 0.0f, 0.0f, 0.0f};
    const int laneoff = q * 256 + fb * 2;   // oct=q: consumer base offset (dwords)

    for (int s = 0; s < T_ + 2; ++s) {
        const int t = s - layer;
        if (t >= 0 && t < T_) {
            const int p_out  = t & 1;
            const int p_prev = (t + 1) & 1;
            const unsigned* xs_l =
                ((layer == 0) ? (xs + (size_t)t * 4096)
                              : (hb_in + (size_t)p_out * 16384)) + laneoff;
            const unsigned* hs_l = hb_l + (size_t)p_prev * 16384 + laneoff;

            f32x4 acc[4] = {{0.f,0.f,0.f,0.f},{0.f,0.f,0.f,0.f},
                            {0.f,0.f,0.f,0.f},{0.f,0.f,0.f,0.f}};
            if (layer == 0) step_mfma<4, false>(xs_l, hs_l, wfrag, lane, acc);
            else            step_mfma<16, true>(xs_l, hs_l, wfrag, lane, acc);

            // In-register finalize: reg g of acc[rg] = gate g of (fb, c0+rg*4+q).
#pragma unroll
            for (int rg = 0; rg < 4; ++rg) {
                float a[4];
#pragma unroll
                for (int g = 0; g < 4; ++g)
                    a[g] = bias[rg][g] + acc[rg][g];

                const float ig = sigmoid_(a[0]);
                const float fg = sigmoid_(a[1]);
                const float gg = tanh_(a[2]);
                const float og = sigmoid_(a[3]);
                c_reg[rg] = fg * c_reg[rg] + ig * gg;
                const float hv = og * tanh_(c_reg[rg]);

                // cols (q,q^1) pair via shfl_xor(16) -> dword; dwords (q=0,q=2)
                // pair via shfl_xor(32) -> u64; q==0 lane stores.
                const unsigned P0 = (unsigned)f2h(hv);
                const unsigned P1 = (unsigned)__shfl_xor((int)P0, 16, 64) & 0xFFFFu;
                const unsigned D  = P0 | (P1 << 16);
                const unsigned D2 = (unsigned)__shfl_xor((int)D, 32, 64);
                if (q == 0) {
                    storec_u64(&hb_l[(size_t)p_out * 16384 + hstore[rg]],
                               ((unsigned long long)D2 << 32) | D);
                }
            }
        }
        gbar(bar_slots, bid, tid, s + 1);
    }

    // ---- FC head. h2 = layer-2 h at t=511 (parity 1), fp16 kquad layout.
    const unsigned* h2u = hbf + (size_t)2 * 32768 + 16384;
    const int fcb = tid & 63;
    if (bid < 64) {
        float part = 0.0f;
        const float* wrow = fcW1 + (size_t)bid * H_ + w * 128;
#pragma unroll 8
        for (int k = 0; k < 128; ++k) {
            const int kk = w * 128 + k;
            const unsigned dv =
                loadc_u32(h2u + (kk >> 2) * 128 + fcb * 2 + ((kk >> 1) & 1));
            const float val = h2f((unsigned short)((dv >> ((kk & 1) * 16)) & 0xFFFFu));
            part = fmaf(wrow[k], val, part);
        }
        redsc[w * 64 + fcb] = part;
        __syncthreads();
        if (tid < 64) {
            float acc2 = fcb1[bid] + redsc[tid] + redsc[64 + tid] +
                         redsc[128 + tid] + redsc[192 + tid];
            storec_f(&h1s[bid * B_ + tid], fmaxf(acc2, 0.0f));
        }
    }
    gbar(bar_slots, bid, tid, T_ + 3);
    if (bid == 0 && tid < 64) {
        float acc2 = fcb2[0];
#pragma unroll
        for (int c = 0; c < 64; ++c)
            acc2 = fmaf(fcW2[c], loadc_f(&h1s[c * B_ + tid]), acc2);
        out[tid] = fmaxf(acc2, 0.0f);
    }
}

// ---------------------------------------------------------------------------
extern "C" void kernel_launch(void* const* d_in, const int* in_sizes, int n_in,
                              void* d_out, int out_size, void* d_ws, size_t ws_size,
                              hipStream_t stream) {
    const float* in    = (const float*)d_in[0];
    const float* Wih0  = (const float*)d_in[1];
    const float* Whh0  = (const float*)d_in[2];
    const float* bih0  = (const float*)d_in[3];
    const float* bhh0  = (const float*)d_in[4];
    const float* Wih1  = (const float*)d_in[5];
    const float* Whh1  = (const float*)d_in[6];
    const float* bih1  = (const float*)d_in[7];
    const float* bhh1  = (const float*)d_in[8];
    const float* Wih2  = (const float*)d_in[9];
    const float* Whh2  = (const float*)d_in[10];
    const float* bih2  = (const float*)d_in[11];
    const float* bhh2  = (const float*)d_in[12];
    const float* fcW1  = (const float*)d_in[13];
    const float* fcb1  = (const float*)d_in[14];
    const float* fcW2  = (const float*)d_in[15];
    const float* fcb2  = (const float*)d_in[16];
    float* outp = (float*)d_out;

    unsigned* xs  = (unsigned*)d_ws;                   // [T][4096] dw     8 MB
    unsigned* hbf = xs + (size_t)T_ * 4096;            // [3][2][16384]  384 KB
    float*    h1s = (float*)(hbf + (size_t)3 * 32768); // [64][64]        16 KB
    int*      bar_slots = (int*)(h1s + 64 * 64);       // NBLK*16 ints

    hipMemsetAsync(hbf, 0,
                   ((size_t)3 * 32768 + 64 * 64 + NBLK * 16 + 16) * sizeof(int),
                   stream);

    transpose_x<<<dim3(T_), dim3(256), 0, stream>>>(in, xs);

    void* args[] = {
        (void*)&xs, (void*)&hbf, (void*)&h1s, (void*)&outp, (void*)&bar_slots,
        (void*)&Wih0, (void*)&Whh0, (void*)&bih0, (void*)&bhh0,
        (void*)&Wih1, (void*)&Whh1, (void*)&bih1, (void*)&bhh1,
        (void*)&Wih2, (void*)&Whh2, (void*)&bih2, (void*)&bhh2,
        (void*)&fcW1, (void*)&fcb1, (void*)&fcW2, (void*)&fcb2};
    hipLaunchCooperativeKernel((void*)lstm_scan, dim3(NBLK), dim3(256), args, 0, stream);
}